// Round 6
// baseline (1853.172 us; speedup 1.0000x reference)
//
#include <hip/hip_runtime.h>
#include <math.h>

#define N_TOK 2048
#define BATCH 64
#define DIN   768
#define DMID  512
#define DOUT  128
#define TILE  32    // rows per work item
#define KC    64    // k-chunk of x staged in LDS
#define MC    128   // D_MID chunk per pass (4 passes)
#define GRID_B 1536 // 6 blocks/CU * 256 CUs
#define MAX_ITEMS 4096  // static bound: 64 segments * <=33 tiles each = 2112

// Float atomic max via int/uint trick (order-preserving for IEEE-754).
__device__ __forceinline__ void atomicMaxFloat(float* addr, float val) {
    if (val >= 0.0f) atomicMax((int*)addr, __float_as_int(val));
    else             atomicMin((unsigned int*)addr, __float_as_uint(val));
}

__global__ void init_kernel(float* __restrict__ x1) {
    int i = blockIdx.x * blockDim.x + threadIdx.x;
    if (i < BATCH * DOUT) x1[i] = -INFINITY;
}

// 1 block / 1 wave of 64 threads: build compact work list in ws.
// ws[0] = n_items; ws[1+i] = (b << 16) | tile_index.
__global__ void build_kernel(const int* __restrict__ batch_list, int* __restrict__ ws) {
    const int b     = threadIdx.x;          // 0..63
    const int start = (b == 0) ? 0 : batch_list[b - 1];
    const int len   = batch_list[b];
    const int end   = start + len;          // <= 2046, segments non-empty
    const int t0    = start >> 5;           // TILE = 32
    const int t1    = (end - 1) >> 5;
    const int n     = t1 - t0 + 1;

    // inclusive scan over the single 64-lane wave
    int incl = n;
    #pragma unroll
    for (int d = 1; d < 64; d <<= 1) {
        int y = __shfl_up(incl, d);
        if (b >= d) incl += y;
    }
    const int excl = incl - n;
    if (b == 63) ws[0] = incl;              // total item count
    for (int t = 0; t < n; ++t)
        ws[1 + excl + t] = (b << 16) | (t0 + t);
}

// Balanced worker: grid-strides over compacted items. One item = 32 rows of one b.
// Thread map: 8 row-groups (4 rows) x 32 col-groups (4 cols).
__global__ __launch_bounds__(256, 6) void fused_kernel(
    const float* __restrict__ x,   // (N, B, DIN)
    const float* __restrict__ W1,  // (DIN, DMID)
    const float* __restrict__ b1,  // (DMID)
    const float* __restrict__ W2,  // (DMID, DOUT)
    const float* __restrict__ b2,  // (DOUT)
    const int*   __restrict__ batch_list,
    const int*   __restrict__ ws,
    float* __restrict__ x1)        // (B, DOUT), pre-set to -inf
{
    __shared__ float xs[TILE][KC];   // 8 KB; reused as reduce buf
    __shared__ float hs[TILE][MC];   // 16 KB

    const int tid = threadIdx.x;
    const int tr  = tid >> 5;   // 0..7  (rows tr*4 .. +3)
    const int tc  = tid & 31;   // 0..31 (cols tc*4 .. +3)

    // Defensive clamp: worker's footprint stays bounded even against a
    // corrupt/stale workspace (can't hang the container on OOB).
    int n_items = ws[0];
    n_items = (n_items < 0) ? 0 : ((n_items > MAX_ITEMS) ? MAX_ITEMS : n_items);

    for (int it = blockIdx.x; it < n_items; it += GRID_B) {
        const int item = ws[1 + it];
        const int b    = (item >> 16) & (BATCH - 1);            // masked to [0,64)
        const int row0 = (item & (N_TOK / TILE - 1)) * TILE;    // masked to [0,2048)
        const int start = (b == 0) ? 0 : batch_list[b - 1];
        const int end   = start + batch_list[b];

        float acc2[4][4];
        #pragma unroll
        for (int r = 0; r < 4; ++r)
            #pragma unroll
            for (int c = 0; c < 4; ++c) acc2[r][c] = 0.0f;

        for (int mc = 0; mc < DMID; mc += MC) {
            // ---- GEMM1 chunk: hs[32][128] = relu(x_tile @ W1[:, mc:mc+128] + b1) ----
            float acc1[4][4];
            #pragma unroll
            for (int r = 0; r < 4; ++r)
                #pragma unroll
                for (int c = 0; c < 4; ++c) acc1[r][c] = 0.0f;

            const float* W1c = W1 + mc + tc * 4;

            for (int kc = 0; kc < DIN; kc += KC) {
                __syncthreads();  // guards xs overwrite (and prior hs/red reads)
                // stage x chunk: 32 rows x 64 k = 512 float4, 2 per thread
                #pragma unroll
                for (int j = 0; j < 2; ++j) {
                    const int i  = tid + j * 256;
                    const int r  = i >> 4;     // 0..31
                    const int kq = i & 15;     // 0..15
                    *(float4*)&xs[r][kq * 4] =
                        *(const float4*)&x[((size_t)(row0 + r) * BATCH + b) * DIN + kc + kq * 4];
                }
                __syncthreads();

                #pragma unroll 4
                for (int k = 0; k < KC; ++k) {
                    const float4 w = *(const float4*)&W1c[(size_t)(kc + k) * DMID];
                    float xv[4];
                    #pragma unroll
                    for (int r = 0; r < 4; ++r) xv[r] = xs[tr * 4 + r][k];
                    #pragma unroll
                    for (int r = 0; r < 4; ++r) {
                        acc1[r][0] = fmaf(xv[r], w.x, acc1[r][0]);
                        acc1[r][1] = fmaf(xv[r], w.y, acc1[r][1]);
                        acc1[r][2] = fmaf(xv[r], w.z, acc1[r][2]);
                        acc1[r][3] = fmaf(xv[r], w.w, acc1[r][3]);
                    }
                }
            }

            // bias + relu -> hs (prior-mc hs reads ended before this mc's first sync)
            {
                const float4 bb = *(const float4*)&b1[mc + tc * 4];
                #pragma unroll
                for (int r = 0; r < 4; ++r) {
                    float4 hv;
                    hv.x = fmaxf(acc1[r][0] + bb.x, 0.0f);
                    hv.y = fmaxf(acc1[r][1] + bb.y, 0.0f);
                    hv.z = fmaxf(acc1[r][2] + bb.z, 0.0f);
                    hv.w = fmaxf(acc1[r][3] + bb.w, 0.0f);
                    *(float4*)&hs[tr * 4 + r][tc * 4] = hv;
                }
            }
            __syncthreads();

            // ---- GEMM2 partial: acc2 += hs @ W2[mc:mc+128, :] ----
            const float* W2c = W2 + (size_t)mc * DOUT + tc * 4;
            #pragma unroll 4
            for (int kk = 0; kk < MC; ++kk) {
                const float4 w = *(const float4*)&W2c[(size_t)kk * DOUT];
                float hv[4];
                #pragma unroll
                for (int r = 0; r < 4; ++r) hv[r] = hs[tr * 4 + r][kk];
                #pragma unroll
                for (int r = 0; r < 4; ++r) {
                    acc2[r][0] = fmaf(hv[r], w.x, acc2[r][0]);
                    acc2[r][1] = fmaf(hv[r], w.y, acc2[r][1]);
                    acc2[r][2] = fmaf(hv[r], w.z, acc2[r][2]);
                    acc2[r][3] = fmaf(hv[r], w.w, acc2[r][3]);
                }
            }
            // next mc's first staging sync guards hs rewrite
        }

        // ---- bias + segment mask + per-thread column max ----
        const float4 bb2 = *(const float4*)&b2[tc * 4];
        float cmax[4] = {-INFINITY, -INFINITY, -INFINITY, -INFINITY};
        #pragma unroll
        for (int r = 0; r < 4; ++r) {
            const int row = row0 + tr * 4 + r;
            const bool in = (row >= start) && (row < end);
            #pragma unroll
            for (int c = 0; c < 4; ++c) {
                const float v = acc2[r][c] + ((const float*)&bb2)[c];
                if (in) cmax[c] = fmaxf(cmax[c], v);
            }
        }

        // block reduce over 8 row-groups (reuse xs as [8][DOUT]); all threads
        // passed the GEMM2-entry sync, so xs (GEMM1 reads) is quiescent.
        float (*red)[DOUT] = (float(*)[DOUT])xs;
        #pragma unroll
        for (int c = 0; c < 4; ++c) red[tr][tc * 4 + c] = cmax[c];
        __syncthreads();

        if (tid < DOUT) {
            float m = red[0][tid];
            #pragma unroll
            for (int r = 1; r < 8; ++r) m = fmaxf(m, red[r][tid]);
            atomicMaxFloat(&x1[b * DOUT + tid], m);
        }
        // next item's first staging sync guards red/xs reuse
    }
}

// argmax(softmax(x1)) == argmax(x1); first-index tie semantics match strict >.
__global__ void argmax_kernel(const float* __restrict__ x1, float* __restrict__ probs) {
    int b = blockIdx.x * blockDim.x + threadIdx.x;
    if (b >= BATCH) return;
    const float* row = x1 + b * DOUT;
    float best = row[0];
    int bi = 0;
    for (int c = 1; c < DOUT; ++c) {
        float v = row[c];
        if (v > best) { best = v; bi = c; }
    }
    probs[b] = (float)bi;
}

extern "C" void kernel_launch(void* const* d_in, const int* in_sizes, int n_in,
                              void* d_out, int out_size, void* d_ws, size_t ws_size,
                              hipStream_t stream) {
    const float* x          = (const float*)d_in[0];
    const float* W1         = (const float*)d_in[1];
    const float* b1         = (const float*)d_in[2];
    const float* W2         = (const float*)d_in[3];
    const float* b2         = (const float*)d_in[4];
    const int*   batch_list = (const int*)d_in[5];

    float* x1    = (float*)d_out;          // 64*128
    float* probs = x1 + BATCH * DOUT;      // 64
    int*   ws    = (int*)d_ws;             // [count, items...] (~2.2K ints max)

    init_kernel<<<(BATCH * DOUT + 255) / 256, 256, 0, stream>>>(x1);
    build_kernel<<<1, 64, 0, stream>>>(batch_list, ws);
    fused_kernel<<<GRID_B, 256, 0, stream>>>(x, W1, b1, W2, b2, batch_list, ws, x1);
    argmax_kernel<<<1, 64, 0, stream>>>(x1, probs);
}